// Round 9
// baseline (611.864 us; speedup 1.0000x reference)
//
#include <hip/hip_runtime.h>
#include <stdint.h>

#define B 8
#define S 128
#define D 512
#define NIN 1024
#define NOUT 1024
#define T 32

typedef __attribute__((ext_vector_type(8))) short short8;
typedef __attribute__((ext_vector_type(4))) float floatx4;

// ---------------------------------------------------------------------------
// Generic fp32 tiled GEMM: C[M,N] = maybe_relu(A[M,K] @ Bm[K,N] + bias[N])
// ---------------------------------------------------------------------------
__global__ __launch_bounds__(256) void k_gemm(const float* __restrict__ A,
                                              const float* __restrict__ Bm,
                                              const float* __restrict__ bias,
                                              float* __restrict__ C,
                                              int M, int N, int K, int relu)
{
    __shared__ float As[16][64];
    __shared__ float Bs[16][64];
    const int tid = threadIdx.x;
    const int bx = blockIdx.x, by = blockIdx.y;
    const int tx = tid & 15, ty = tid >> 4;
    const int ar = tid >> 2, ak = (tid & 3) << 2;
    const int bk = tid >> 4, bc = (tid & 15) << 2;
    float acc[4][4] = {{0.f,0.f,0.f,0.f},{0.f,0.f,0.f,0.f},
                       {0.f,0.f,0.f,0.f},{0.f,0.f,0.f,0.f}};
    for (int k0 = 0; k0 < K; k0 += 16) {
        float4 a4 = *(const float4*)(A + (size_t)(by*64 + ar)*K + k0 + ak);
        float4 b4 = *(const float4*)(Bm + (size_t)(k0 + bk)*N + bx*64 + bc);
        __syncthreads();
        As[ak+0][ar] = a4.x; As[ak+1][ar] = a4.y;
        As[ak+2][ar] = a4.z; As[ak+3][ar] = a4.w;
        *(float4*)&Bs[bk][bc] = b4;
        __syncthreads();
        #pragma unroll
        for (int kk = 0; kk < 16; ++kk) {
            float4 av = *(const float4*)&As[kk][ty << 2];
            float4 bv = *(const float4*)&Bs[kk][tx << 2];
            acc[0][0] = fmaf(av.x, bv.x, acc[0][0]);
            acc[0][1] = fmaf(av.x, bv.y, acc[0][1]);
            acc[0][2] = fmaf(av.x, bv.z, acc[0][2]);
            acc[0][3] = fmaf(av.x, bv.w, acc[0][3]);
            acc[1][0] = fmaf(av.y, bv.x, acc[1][0]);
            acc[1][1] = fmaf(av.y, bv.y, acc[1][1]);
            acc[1][2] = fmaf(av.y, bv.z, acc[1][2]);
            acc[1][3] = fmaf(av.y, bv.w, acc[1][3]);
            acc[2][0] = fmaf(av.z, bv.x, acc[2][0]);
            acc[2][1] = fmaf(av.z, bv.y, acc[2][1]);
            acc[2][2] = fmaf(av.z, bv.z, acc[2][2]);
            acc[2][3] = fmaf(av.z, bv.w, acc[2][3]);
            acc[3][0] = fmaf(av.w, bv.x, acc[3][0]);
            acc[3][1] = fmaf(av.w, bv.y, acc[3][1]);
            acc[3][2] = fmaf(av.w, bv.z, acc[3][2]);
            acc[3][3] = fmaf(av.w, bv.w, acc[3][3]);
        }
    }
    const int row0 = by*64 + (ty << 2), col0 = bx*64 + (tx << 2);
    float4 bb = *(const float4*)(bias + col0);
    #pragma unroll
    for (int i = 0; i < 4; ++i) {
        float4 o;
        o.x = acc[i][0] + bb.x; o.y = acc[i][1] + bb.y;
        o.z = acc[i][2] + bb.z; o.w = acc[i][3] + bb.w;
        if (relu) {
            o.x = fmaxf(o.x, 0.f); o.y = fmaxf(o.y, 0.f);
            o.z = fmaxf(o.z, 0.f); o.w = fmaxf(o.w, 0.f);
        }
        *(float4*)(C + (size_t)(row0 + i)*N + col0) = o;
    }
}

// ---------------------------------------------------------------------------
// Input LIF phase A: bare serial chain, next-position prefetch.
// sbits layout: [b*S+s][n] u32 (bit = t)
// ---------------------------------------------------------------------------
__global__ __launch_bounds__(256) void k_lif_inA(const float* __restrict__ snn,
                                                 unsigned int* __restrict__ sbits,
                                                 unsigned int* __restrict__ counters)
{
    const int tid = blockIdx.x * 256 + threadIdx.x;   // 0..8191
    const int b = tid >> 10, n = tid & (NIN - 1);
    const float* cur = snn + (size_t)(b * S) * NIN + n;
    float v = 0.f;
    int cnt = 0;
    float I = cur[0];
    for (int s = 0; s < S; ++s) {
        const float In = (s + 1 < S) ? cur[(size_t)(s + 1) * NIN] : 0.f;
        unsigned int bits = 0u;
        #pragma unroll
        for (int t = 0; t < T; ++t) {
            v = __fadd_rn(__fmul_rn(0.9f, v), I);
            const bool sp = (v >= 1.0f);
            v = sp ? (v - 1.0f) : v;
            bits |= (sp ? 1u : 0u) << t;
        }
        sbits[(size_t)(b * S + s) * NIN + n] = bits;
        cnt += __popc(bits);
        I = In;
    }
    atomicAdd(counters, (unsigned int)cnt);
}

// ---------------------------------------------------------------------------
// Input LIF phase B: parallel rebuild of the u64 ballot masks.
// masks layout: [(b*S+s)*T + t][wq] u64 x16 (bit = n - wq*64)
// ---------------------------------------------------------------------------
__global__ __launch_bounds__(256) void k_lif_inB(const unsigned int* __restrict__ sbits,
                                                 unsigned long long* __restrict__ masks)
{
    const int bs = blockIdx.x;                 // b*S+s
    const int w = threadIdx.x >> 6, lane = threadIdx.x & 63;
    #pragma unroll
    for (int i = 0; i < 4; ++i) {
        const int wq = w * 4 + i;
        const unsigned int bits = sbits[(size_t)bs * NIN + wq * 64 + lane];
        #pragma unroll
        for (int t = 0; t < T; ++t) {
            const unsigned long long m = __ballot((bits >> t) & 1u);
            if (lane == 0)
                masks[((size_t)bs * T + t) * 16 + wq] = m;
        }
    }
}

// ---------------------------------------------------------------------------
// Prep: transpose W_conn [k][n] -> WcT [n][k] and split fp32 = bf16_hi+bf16_lo
// ---------------------------------------------------------------------------
__global__ __launch_bounds__(256) void k_prep(const float* __restrict__ Wc,
                                              unsigned short* __restrict__ WhT,
                                              unsigned short* __restrict__ WlT)
{
    __shared__ float tile[64][65];
    const int k0 = blockIdx.x * 64, n0 = blockIdx.y * 64;
    const int tx = threadIdx.x & 63, ty = threadIdx.x >> 6;
    #pragma unroll
    for (int p = 0; p < 16; ++p) {
        const int kl = p*4 + ty;
        tile[kl][tx] = Wc[(size_t)(k0 + kl) * NOUT + n0 + tx];
    }
    __syncthreads();
    #pragma unroll
    for (int p = 0; p < 16; ++p) {
        const int nl = p*4 + ty;
        const float w = tile[tx][nl];
        const unsigned int u  = __float_as_uint(w);
        const unsigned int hb = (u + 0x7FFFu + ((u >> 16) & 1u)) & 0xFFFF0000u; // bf16 RNE
        const float hif = __uint_as_float(hb);
        const float lo  = w - hif;                                             // exact
        const unsigned int ul = __float_as_uint(lo);
        const unsigned short lob = (unsigned short)((ul + 0x7FFFu + ((ul >> 16) & 1u)) >> 16);
        WhT[(size_t)(n0 + nl) * NIN + k0 + tx] = (unsigned short)(hb >> 16);
        WlT[(size_t)(n0 + nl) * NIN + k0 + tx] = lob;
    }
}

// ---------------------------------------------------------------------------
// Spike GEMM via 16x16x32 MFMA. Block = 256 rows x 128 cols, 4 waves in a
// 2x2 arrangement; each wave = 128 rows x 64 cols = 8x4 frags (acc = 128,
// carried in AGPRs as in R8 - VGPR_Count 124, no spill). The f=8 x c=4
// partition doubles B-frag reuse vs R8 (each LDS b128 feeds 8 MFMAs):
// LDS ledger per CU/chunk 5120 -> 3072 cyc vs 2484 MFMA -> ceiling ~81%.
// A decoded from spike bitmasks with a cheap bit-spread (identical values);
// B hi/lo staged via global_load_lds (dst = wave-uniform base + lane*16).
// MFMA k-order per accumulator identical to R8 -> bitwise-identical Iout.
// ---------------------------------------------------------------------------
__global__ __launch_bounds__(256, 2) void k_conn_mfma(
    const uint4* __restrict__ masks128,
    const unsigned short* __restrict__ WhT,
    const unsigned short* __restrict__ WlT,
    float* __restrict__ Iout, int s0, int P)
{
    __shared__ unsigned short Bsm[2 * 4 * 8 * 512];   // 64 KB, fragment order

    const int tid = threadIdx.x;
    const int w = tid >> 6, lane = tid & 63;
    const int r16 = lane & 15, q = lane >> 4;
    const int wr = w >> 1, wc = w & 1;
    const int PT = P * T;
    const int rowwave = blockIdx.x * 256 + wr * 128;
    const int cb = blockIdx.y * 128;
    const int cw = cb + wc * 64;

    // A mask row pointers (8 x uint4 per 1024-bit row), 8 row-frags of 16
    const uint4* aptr[8];
    #pragma unroll
    for (int f = 0; f < 8; ++f) {
        const int r = rowwave + f*16 + r16;
        const int b = r / PT;
        const int grow = (b * S + s0) * T + (r - b * PT);
        aptr[f] = masks128 + (size_t)grow * 8;
    }

    // B staging: 64 slots (slot = mat*32 + kc*8 + cfrag), 16 per wave.
    // hi slots i=0..7: slot = w + 4i (0..31); lo = same + 32.
    const unsigned short* bsrc[8];
    #pragma unroll
    for (int i = 0; i < 8; ++i) {
        const int slot = w + 4 * i;
        const int kc = (slot >> 3) & 3, cf = slot & 7;
        bsrc[i] = WhT + (size_t)(cb + cf*16 + r16) * NIN + kc * 32 + q * 8;
    }
    const size_t loDelta = (size_t)(WlT - WhT);

    floatx4 acc[8][4];
    #pragma unroll
    for (int f = 0; f < 8; ++f)
        #pragma unroll
        for (int c = 0; c < 4; ++c)
            acc[f][c] = (floatx4){0.f, 0.f, 0.f, 0.f};

    const unsigned short* bp = Bsm + (size_t)lane * 8;   // lane term of frag reads

    for (int ch = 0; ch < 8; ++ch) {
        __syncthreads();   // previous chunk's frag reads done
#if __has_builtin(__builtin_amdgcn_global_load_lds)
        #pragma unroll
        for (int i = 0; i < 8; ++i) {
            __builtin_amdgcn_global_load_lds(
                (const __attribute__((address_space(1))) void*)(bsrc[i] + ch * 128),
                (__attribute__((address_space(3))) void*)&Bsm[(w + 4*i) * 512],
                16, 0, 0);
            __builtin_amdgcn_global_load_lds(
                (const __attribute__((address_space(1))) void*)(bsrc[i] + loDelta + ch * 128),
                (__attribute__((address_space(3))) void*)&Bsm[(32 + w + 4*i) * 512],
                16, 0, 0);
        }
#else
        #pragma unroll
        for (int i = 0; i < 8; ++i) {
            const uint4 h = *(const uint4*)(bsrc[i] + ch * 128);
            const uint4 l = *(const uint4*)(bsrc[i] + loDelta + ch * 128);
            *(uint4*)&Bsm[(w + 4*i) * 512 + lane * 8] = h;
            *(uint4*)&Bsm[(32 + w + 4*i) * 512 + lane * 8] = l;
        }
#endif
        uint4 aw[8];
        #pragma unroll
        for (int f = 0; f < 8; ++f) aw[f] = aptr[f][ch];
        __syncthreads();

        #pragma unroll
        for (int kc = 0; kc < 4; ++kc) {
            // decode 8 A-frags (bit-spread: ~14 VALU/byte, same values as before)
            short8 af[8];
            #pragma unroll
            for (int f = 0; f < 8; ++f) {
                const unsigned int word = (kc == 0) ? aw[f].x : (kc == 1) ? aw[f].y
                                         : (kc == 2) ? aw[f].z : aw[f].w;
                const unsigned int byte = (word >> (q * 8)) & 0xFFu;
                const unsigned int t2 = byte | (byte << 15);
                union { unsigned int u[4]; short8 s; } A;
                #pragma unroll
                for (int j = 0; j < 4; ++j)
                    A.u[j] = ((t2 >> (2*j)) & 0x00010001u) * 0x3F80u;
                af[f] = A.s;
            }
            #pragma unroll
            for (int c = 0; c < 4; ++c) {
                const short8 bh = *(const short8*)(bp + ((kc * 8 + wc * 4 + c) << 9));
                const short8 bl = *(const short8*)(bp + ((32 + kc * 8 + wc * 4 + c) << 9));
                #pragma unroll
                for (int f = 0; f < 8; ++f) {
                    acc[f][c] = __builtin_amdgcn_mfma_f32_16x16x32_bf16(af[f], bh, acc[f][c], 0, 0, 0);
                    acc[f][c] = __builtin_amdgcn_mfma_f32_16x16x32_bf16(af[f], bl, acc[f][c], 0, 0, 0);
                }
            }
        }
    }

    // epilogue (verified pattern): C/D col=lane&15, row=(lane>>4)*4+reg
    #pragma unroll
    for (int f = 0; f < 8; ++f) {
        const int row = rowwave + f*16 + q*4;
        #pragma unroll
        for (int c = 0; c < 4; ++c) {
            const int col = cw + c*16 + r16;
            #pragma unroll
            for (int i = 0; i < 4; ++i)
                Iout[(size_t)(row + i) * NOUT + col] = acc[f][c][i];
        }
    }
}

// ---------------------------------------------------------------------------
// Output-population LIF: depth-2 position prefetch (64 loads in flight)
// hides ~900-cyc HBM latency behind the 512-cyc serial chain.
// Chain arithmetic and order identical to previous rounds.
// ---------------------------------------------------------------------------
__global__ __launch_bounds__(256) void k_lif_out(const float* __restrict__ Iout,
                                                 float* __restrict__ vstate,
                                                 float* __restrict__ sacc_out,
                                                 unsigned int* __restrict__ counters,
                                                 int s0, int P, int init)
{
    const int tid = blockIdx.x * 256 + threadIdx.x;
    const int b = tid >> 10, n = tid & (NOUT - 1);
    const int Tc = P * T;
    float v = init ? 0.f : vstate[tid];
    const float* ip = Iout + (size_t)b * Tc * NOUT + n;
    int cnt = 0;

    float c0[T], c1[T];
    #pragma unroll
    for (int t = 0; t < T; ++t) c0[t] = ip[(size_t)t * NOUT];
    if (P > 1) {
        const float* p1 = ip + (size_t)T * NOUT;
        #pragma unroll
        for (int t = 0; t < T; ++t) c1[t] = p1[(size_t)t * NOUT];
    }

    for (int sl = 0; sl < P; sl += 2) {
        float n0[T], n1[T];
        if (sl + 2 < P) {
            const float* p = ip + (size_t)(sl + 2) * T * NOUT;
            #pragma unroll
            for (int t = 0; t < T; ++t) n0[t] = p[(size_t)t * NOUT];
        }
        if (sl + 3 < P) {
            const float* p = ip + (size_t)(sl + 3) * T * NOUT;
            #pragma unroll
            for (int t = 0; t < T; ++t) n1[t] = p[(size_t)t * NOUT];
        }
        {
            float sacc = 0.f;
            #pragma unroll
            for (int t = 0; t < T; ++t) {
                v = __fadd_rn(__fmul_rn(0.9f, v), c0[t]);
                const bool sp = (v >= 1.0f);
                v = sp ? (v - 1.0f) : v;
                sacc += sp ? 1.f : 0.f;
                cnt += sp ? 1 : 0;
            }
            sacc_out[(size_t)(b*S + s0 + sl) * NOUT + n] = sacc;
        }
        if (sl + 1 < P) {
            float sacc = 0.f;
            #pragma unroll
            for (int t = 0; t < T; ++t) {
                v = __fadd_rn(__fmul_rn(0.9f, v), c1[t]);
                const bool sp = (v >= 1.0f);
                v = sp ? (v - 1.0f) : v;
                sacc += sp ? 1.f : 0.f;
                cnt += sp ? 1 : 0;
            }
            sacc_out[(size_t)(b*S + s0 + sl + 1) * NOUT + n] = sacc;
        }
        #pragma unroll
        for (int t = 0; t < T; ++t) { c0[t] = n0[t]; c1[t] = n1[t]; }
    }
    vstate[tid] = v;
    atomicAdd(counters + 1, (unsigned int)cnt);
}

__global__ void k_init(unsigned int* c)
{
    if (threadIdx.x < 2) c[threadIdx.x] = 0u;
}

__global__ void k_rate(const unsigned int* __restrict__ c, float* __restrict__ out)
{
    if (threadIdx.x == 0 && blockIdx.x == 0) {
        const float total = (float)c[0] + (float)c[1];
        out[0] = total / (float)(B * S * (NIN + NOUT) * T);
    }
}

// ---------------------------------------------------------------------------
extern "C" void kernel_launch(void* const* d_in, const int* in_sizes, int n_in,
                              void* d_out, int out_size, void* d_ws, size_t ws_size,
                              hipStream_t stream)
{
    const float* E    = (const float*)d_in[0];
    const float* Win  = (const float*)d_in[1];
    const float* bin  = (const float*)d_in[2];
    const float* Wc   = (const float*)d_in[3];
    const float* Wout = (const float*)d_in[4];
    const float* bout = (const float*)d_in[5];
    float* out = (float*)d_out;

    char* w = (char*)d_ws;
    float* snn              = (float*)(w);                          // 4 MB (later reused for WcT)
    unsigned short* WhT     = (unsigned short*)(w);                 // 2 MB (aliases snn, after lif_inA)
    unsigned short* WlT     = (unsigned short*)(w + (2 << 20));     // 2 MB
    unsigned long long* msk = (unsigned long long*)(w + (4 << 20)); // 4 MB
    float* sacc             = (float*)(w + (8 << 20));              // 4 MB
    unsigned int* sbits     = (unsigned int*)(w + (8 << 20));       // 4 MB (aliases sacc; dead before lif_out)
    float* vst              = (float*)(w + (12 << 20));             // 32 KB
    unsigned int* cnt       = (unsigned int*)(w + (12 << 20) + (64 << 10));
    float* Iout             = (float*)(w + (13 << 20));

    const size_t base = (size_t)13 << 20;
    const size_t avail = (ws_size > base) ? (ws_size - base) : 0;
    int P = 1;
    if      (avail >= (size_t)B * 128 * T * NOUT * 4) P = 128;
    else if (avail >= (size_t)B *  16 * T * NOUT * 4) P = 16;
    else if (avail >= (size_t)B *   4 * T * NOUT * 4) P = 4;

    k_init<<<1, 64, 0, stream>>>(cnt);

    dim3 g1(NIN / 64, (B * S) / 64);
    k_gemm<<<g1, 256, 0, stream>>>(E, Win, bin, snn, B * S, NIN, D, 1);

    k_lif_inA<<<32, 256, 0, stream>>>(snn, sbits, cnt);
    k_lif_inB<<<B * S, 256, 0, stream>>>(sbits, msk);

    // snn is dead now: build transposed hi/lo bf16 split of W_conn in its place
    dim3 gp(NIN / 64, NOUT / 64);
    k_prep<<<gp, 256, 0, stream>>>(Wc, WhT, WlT);

    for (int c = 0; c < S / P; ++c) {
        dim3 gc((B * P * T) / 256, NOUT / 128);
        k_conn_mfma<<<gc, 256, 0, stream>>>((const uint4*)msk, WhT, WlT, Iout, c * P, P);
        k_lif_out<<<32, 256, 0, stream>>>(Iout, vst, sacc, cnt, c * P, P, c == 0 ? 1 : 0);
    }

    dim3 g2(D / 64, (B * S) / 64);
    k_gemm<<<g2, 256, 0, stream>>>(sacc, Wout, bout, out, B * S, D, NOUT, 0);

    k_rate<<<1, 64, 0, stream>>>(cnt, out + (size_t)B * S * D);
}

// Round 10
// 484.741 us; speedup vs baseline: 1.2623x; 1.2623x over previous
//
#include <hip/hip_runtime.h>
#include <stdint.h>

#define B 8
#define S 128
#define D 512
#define NIN 1024
#define NOUT 1024
#define T 32

typedef __attribute__((ext_vector_type(8))) short short8;
typedef __attribute__((ext_vector_type(4))) float floatx4;

// ---------------------------------------------------------------------------
// Generic fp32 tiled GEMM: C[M,N] = maybe_relu(A[M,K] @ Bm[K,N] + bias[N])
// ---------------------------------------------------------------------------
__global__ __launch_bounds__(256) void k_gemm(const float* __restrict__ A,
                                              const float* __restrict__ Bm,
                                              const float* __restrict__ bias,
                                              float* __restrict__ C,
                                              int M, int N, int K, int relu)
{
    __shared__ float As[16][64];
    __shared__ float Bs[16][64];
    const int tid = threadIdx.x;
    const int bx = blockIdx.x, by = blockIdx.y;
    const int tx = tid & 15, ty = tid >> 4;
    const int ar = tid >> 2, ak = (tid & 3) << 2;
    const int bk = tid >> 4, bc = (tid & 15) << 2;
    float acc[4][4] = {{0.f,0.f,0.f,0.f},{0.f,0.f,0.f,0.f},
                       {0.f,0.f,0.f,0.f},{0.f,0.f,0.f,0.f}};
    for (int k0 = 0; k0 < K; k0 += 16) {
        float4 a4 = *(const float4*)(A + (size_t)(by*64 + ar)*K + k0 + ak);
        float4 b4 = *(const float4*)(Bm + (size_t)(k0 + bk)*N + bx*64 + bc);
        __syncthreads();
        As[ak+0][ar] = a4.x; As[ak+1][ar] = a4.y;
        As[ak+2][ar] = a4.z; As[ak+3][ar] = a4.w;
        *(float4*)&Bs[bk][bc] = b4;
        __syncthreads();
        #pragma unroll
        for (int kk = 0; kk < 16; ++kk) {
            float4 av = *(const float4*)&As[kk][ty << 2];
            float4 bv = *(const float4*)&Bs[kk][tx << 2];
            acc[0][0] = fmaf(av.x, bv.x, acc[0][0]);
            acc[0][1] = fmaf(av.x, bv.y, acc[0][1]);
            acc[0][2] = fmaf(av.x, bv.z, acc[0][2]);
            acc[0][3] = fmaf(av.x, bv.w, acc[0][3]);
            acc[1][0] = fmaf(av.y, bv.x, acc[1][0]);
            acc[1][1] = fmaf(av.y, bv.y, acc[1][1]);
            acc[1][2] = fmaf(av.y, bv.z, acc[1][2]);
            acc[1][3] = fmaf(av.y, bv.w, acc[1][3]);
            acc[2][0] = fmaf(av.z, bv.x, acc[2][0]);
            acc[2][1] = fmaf(av.z, bv.y, acc[2][1]);
            acc[2][2] = fmaf(av.z, bv.z, acc[2][2]);
            acc[2][3] = fmaf(av.z, bv.w, acc[2][3]);
            acc[3][0] = fmaf(av.w, bv.x, acc[3][0]);
            acc[3][1] = fmaf(av.w, bv.y, acc[3][1]);
            acc[3][2] = fmaf(av.w, bv.z, acc[3][2]);
            acc[3][3] = fmaf(av.w, bv.w, acc[3][3]);
        }
    }
    const int row0 = by*64 + (ty << 2), col0 = bx*64 + (tx << 2);
    float4 bb = *(const float4*)(bias + col0);
    #pragma unroll
    for (int i = 0; i < 4; ++i) {
        float4 o;
        o.x = acc[i][0] + bb.x; o.y = acc[i][1] + bb.y;
        o.z = acc[i][2] + bb.z; o.w = acc[i][3] + bb.w;
        if (relu) {
            o.x = fmaxf(o.x, 0.f); o.y = fmaxf(o.y, 0.f);
            o.z = fmaxf(o.z, 0.f); o.w = fmaxf(o.w, 0.f);
        }
        *(float4*)(C + (size_t)(row0 + i)*N + col0) = o;
    }
}

// ---------------------------------------------------------------------------
// Input LIF phase A: bare serial chain, next-position prefetch.
// sbits layout: [b*S+s][n] u32 (bit = t)
// ---------------------------------------------------------------------------
__global__ __launch_bounds__(256) void k_lif_inA(const float* __restrict__ snn,
                                                 unsigned int* __restrict__ sbits,
                                                 unsigned int* __restrict__ counters)
{
    const int tid = blockIdx.x * 256 + threadIdx.x;   // 0..8191
    const int b = tid >> 10, n = tid & (NIN - 1);
    const float* cur = snn + (size_t)(b * S) * NIN + n;
    float v = 0.f;
    int cnt = 0;
    float I = cur[0];
    for (int s = 0; s < S; ++s) {
        const float In = (s + 1 < S) ? cur[(size_t)(s + 1) * NIN] : 0.f;
        unsigned int bits = 0u;
        #pragma unroll
        for (int t = 0; t < T; ++t) {
            v = __fadd_rn(__fmul_rn(0.9f, v), I);
            const bool sp = (v >= 1.0f);
            v = sp ? (v - 1.0f) : v;
            bits |= (sp ? 1u : 0u) << t;
        }
        sbits[(size_t)(b * S + s) * NIN + n] = bits;
        cnt += __popc(bits);
        I = In;
    }
    atomicAdd(counters, (unsigned int)cnt);
}

// ---------------------------------------------------------------------------
// Input LIF phase B: parallel rebuild of the u64 ballot masks.
// masks layout: [(b*S+s)*T + t][wq] u64 x16 (bit = n - wq*64)
// ---------------------------------------------------------------------------
__global__ __launch_bounds__(256) void k_lif_inB(const unsigned int* __restrict__ sbits,
                                                 unsigned long long* __restrict__ masks)
{
    const int bs = blockIdx.x;                 // b*S+s
    const int w = threadIdx.x >> 6, lane = threadIdx.x & 63;
    #pragma unroll
    for (int i = 0; i < 4; ++i) {
        const int wq = w * 4 + i;
        const unsigned int bits = sbits[(size_t)bs * NIN + wq * 64 + lane];
        #pragma unroll
        for (int t = 0; t < T; ++t) {
            const unsigned long long m = __ballot((bits >> t) & 1u);
            if (lane == 0)
                masks[((size_t)bs * T + t) * 16 + wq] = m;
        }
    }
}

// ---------------------------------------------------------------------------
// Prep: transpose W_conn [k][n] -> WcT [n][k] and split fp32 = bf16_hi+bf16_lo
// ---------------------------------------------------------------------------
__global__ __launch_bounds__(256) void k_prep(const float* __restrict__ Wc,
                                              unsigned short* __restrict__ WhT,
                                              unsigned short* __restrict__ WlT)
{
    __shared__ float tile[64][65];
    const int k0 = blockIdx.x * 64, n0 = blockIdx.y * 64;
    const int tx = threadIdx.x & 63, ty = threadIdx.x >> 6;
    #pragma unroll
    for (int p = 0; p < 16; ++p) {
        const int kl = p*4 + ty;
        tile[kl][tx] = Wc[(size_t)(k0 + kl) * NOUT + n0 + tx];
    }
    __syncthreads();
    #pragma unroll
    for (int p = 0; p < 16; ++p) {
        const int nl = p*4 + ty;
        const float w = tile[tx][nl];
        const unsigned int u  = __float_as_uint(w);
        const unsigned int hb = (u + 0x7FFFu + ((u >> 16) & 1u)) & 0xFFFF0000u; // bf16 RNE
        const float hif = __uint_as_float(hb);
        const float lo  = w - hif;                                             // exact
        const unsigned int ul = __float_as_uint(lo);
        const unsigned short lob = (unsigned short)((ul + 0x7FFFu + ((ul >> 16) & 1u)) >> 16);
        WhT[(size_t)(n0 + nl) * NIN + k0 + tx] = (unsigned short)(hb >> 16);
        WlT[(size_t)(n0 + nl) * NIN + k0 + tx] = lob;
    }
}

// ---------------------------------------------------------------------------
// Spike GEMM via 16x16x32 MFMA. Block = 256 rows x 128 cols, 4 waves 2x2;
// wave = 128 rows x 64 cols = 8x4 frags (acc = 128 AGPRs). The f=8 x c=4
// partition doubles B-frag reuse vs R8; the R9 spill is avoided by keeping
// spike masks in LDS (Msm, 2 KB/chunk) instead of registers: no aw[8]/aptr[8]
// (-48 VGPRs). BK=64 chunks -> Bsm 32 KB (34 KB total, 2 blocks/CU). B staged
// via global_load_lds width-16 (dst = wave-uniform base + lane*16, the
// verified R9 pattern). MFMA k-order per accumulator identical to R6/R8 ->
// bitwise-identical Iout (absmax stays 0.25). Epilogue = verified pattern.
// ---------------------------------------------------------------------------
__global__ __launch_bounds__(256, 2) void k_conn_mfma(
    const unsigned long long* __restrict__ masks64,
    const unsigned short* __restrict__ WhT,
    const unsigned short* __restrict__ WlT,
    float* __restrict__ Iout, int s0, int P)
{
    __shared__ unsigned short Bsm[32 * 512];        // 32 KB, fragment order
    __shared__ unsigned long long Msm[256];         // 2 KB, one u64 per block-row

    const int tid = threadIdx.x;
    const int w = tid >> 6, lane = tid & 63;
    const int r16 = lane & 15, q = lane >> 4;
    const int wr = w >> 1, wc = w & 1;
    const int PT = P * T;
    const int rowwave = blockIdx.x * 256 + wr * 128;
    const int cb = blockIdx.y * 128;
    const int cw = cb + wc * 64;

    // A staging source: this thread owns block row tid
    const unsigned long long* mrow;
    {
        const int r = blockIdx.x * 256 + tid;
        const int b = r / PT;
        const int grow = (b * S + s0) * T + (r - b * PT);
        mrow = masks64 + (size_t)grow * 16;
    }

    // B staging: 32 slots (slot = mat*16 + kc2*8 + cf), 8 per (wave,i).
    // slot = (tid>>6) + 4*i; staged cooperatively: dst uniform base+lane*16.
    const unsigned short* bsrc[8];
    #pragma unroll
    for (int i = 0; i < 8; ++i) {
        const int slot = w + 4 * i;
        const int mat = slot >> 4, rest = slot & 15;
        const int kc2 = rest >> 3, cf = rest & 7;
        bsrc[i] = (mat ? WlT : WhT)
                + (size_t)(cb + cf * 16 + r16) * NIN + kc2 * 32 + q * 8;
    }

    floatx4 acc[8][4];
    #pragma unroll
    for (int f = 0; f < 8; ++f)
        #pragma unroll
        for (int c = 0; c < 4; ++c)
            acc[f][c] = (floatx4){0.f, 0.f, 0.f, 0.f};

    const unsigned short* bp = Bsm + (size_t)lane * 8;      // lane term
    const unsigned int* Msm32 = (const unsigned int*)Msm;

    for (int ch = 0; ch < 16; ++ch) {
        __syncthreads();   // previous chunk's frag reads done
        // stage B: 8 global_load_lds per wave (each loads 1 KB slot)
        #pragma unroll
        for (int i = 0; i < 8; ++i) {
            __builtin_amdgcn_global_load_lds(
                (const __attribute__((address_space(1))) void*)(bsrc[i] + ch * 64),
                (__attribute__((address_space(3))) void*)&Bsm[(w + 4 * i) * 512],
                16, 0, 0);
        }
        // stage A masks: one u64 per row
        Msm[tid] = mrow[ch];
        __syncthreads();

        #pragma unroll
        for (int kc2 = 0; kc2 < 2; ++kc2) {
            // decode 8 A-frags from LDS mask words (values identical to prior rounds)
            short8 af[8];
            #pragma unroll
            for (int f = 0; f < 8; ++f) {
                const int row = wr * 128 + f * 16 + r16;
                const unsigned int word = Msm32[row * 2 + kc2];
                const unsigned int byte = (word >> (q * 8)) & 0xFFu;
                const unsigned int t2 = byte | (byte << 15);
                union { unsigned int u[4]; short8 s; } A;
                #pragma unroll
                for (int j = 0; j < 4; ++j)
                    A.u[j] = ((t2 >> (2 * j)) & 0x00010001u) * 0x3F80u;
                af[f] = A.s;
            }
            #pragma unroll
            for (int c = 0; c < 4; ++c) {
                const short8 bh = *(const short8*)(bp + ((kc2 * 8 + wc * 4 + c) << 9));
                const short8 bl = *(const short8*)(bp + ((16 + kc2 * 8 + wc * 4 + c) << 9));
                #pragma unroll
                for (int f = 0; f < 8; ++f) {
                    acc[f][c] = __builtin_amdgcn_mfma_f32_16x16x32_bf16(af[f], bh, acc[f][c], 0, 0, 0);
                    acc[f][c] = __builtin_amdgcn_mfma_f32_16x16x32_bf16(af[f], bl, acc[f][c], 0, 0, 0);
                }
            }
        }
    }

    // epilogue (verified pattern): C/D col=lane&15, row=(lane>>4)*4+reg
    #pragma unroll
    for (int f = 0; f < 8; ++f) {
        const int row = rowwave + f * 16 + q * 4;
        #pragma unroll
        for (int c = 0; c < 4; ++c) {
            const int col = cw + c * 16 + r16;
            #pragma unroll
            for (int i = 0; i < 4; ++i)
                Iout[(size_t)(row + i) * NOUT + col] = acc[f][c][i];
        }
    }
}

// ---------------------------------------------------------------------------
// Output-population LIF: next-position register prefetch (R8 version).
// ---------------------------------------------------------------------------
__global__ __launch_bounds__(256) void k_lif_out(const float* __restrict__ Iout,
                                                 float* __restrict__ vstate,
                                                 float* __restrict__ sacc_out,
                                                 unsigned int* __restrict__ counters,
                                                 int s0, int P, int init)
{
    const int tid = blockIdx.x * 256 + threadIdx.x;
    const int b = tid >> 10, n = tid & (NOUT - 1);
    const int Tc = P * T;
    float v = init ? 0.f : vstate[tid];
    const float* ip = Iout + (size_t)b * Tc * NOUT + n;
    int cnt = 0;

    float cur[T];
    #pragma unroll
    for (int t = 0; t < T; ++t) cur[t] = ip[(size_t)t * NOUT];

    for (int sl = 0; sl < P; ++sl) {
        float nxt[T];
        const bool has = (sl + 1 < P);
        if (has) {
            const float* ip2 = ip + (size_t)(sl + 1) * T * NOUT;
            #pragma unroll
            for (int t = 0; t < T; ++t) nxt[t] = ip2[(size_t)t * NOUT];
        }
        float sacc = 0.f;
        #pragma unroll
        for (int t = 0; t < T; ++t) {
            v = __fadd_rn(__fmul_rn(0.9f, v), cur[t]);
            const bool sp = (v >= 1.0f);
            v = sp ? (v - 1.0f) : v;
            sacc += sp ? 1.f : 0.f;
            cnt += sp ? 1 : 0;
        }
        sacc_out[(size_t)(b*S + s0 + sl) * NOUT + n] = sacc;
        if (has) {
            #pragma unroll
            for (int t = 0; t < T; ++t) cur[t] = nxt[t];
        }
    }
    vstate[tid] = v;
    atomicAdd(counters + 1, (unsigned int)cnt);
}

__global__ void k_init(unsigned int* c)
{
    if (threadIdx.x < 2) c[threadIdx.x] = 0u;
}

__global__ void k_rate(const unsigned int* __restrict__ c, float* __restrict__ out)
{
    if (threadIdx.x == 0 && blockIdx.x == 0) {
        const float total = (float)c[0] + (float)c[1];
        out[0] = total / (float)(B * S * (NIN + NOUT) * T);
    }
}

// ---------------------------------------------------------------------------
extern "C" void kernel_launch(void* const* d_in, const int* in_sizes, int n_in,
                              void* d_out, int out_size, void* d_ws, size_t ws_size,
                              hipStream_t stream)
{
    const float* E    = (const float*)d_in[0];
    const float* Win  = (const float*)d_in[1];
    const float* bin  = (const float*)d_in[2];
    const float* Wc   = (const float*)d_in[3];
    const float* Wout = (const float*)d_in[4];
    const float* bout = (const float*)d_in[5];
    float* out = (float*)d_out;

    char* w = (char*)d_ws;
    float* snn              = (float*)(w);                          // 4 MB (later reused for WcT)
    unsigned short* WhT     = (unsigned short*)(w);                 // 2 MB (aliases snn, after lif_inA)
    unsigned short* WlT     = (unsigned short*)(w + (2 << 20));     // 2 MB
    unsigned long long* msk = (unsigned long long*)(w + (4 << 20)); // 4 MB
    float* sacc             = (float*)(w + (8 << 20));              // 4 MB
    unsigned int* sbits     = (unsigned int*)(w + (8 << 20));       // 4 MB (aliases sacc; dead before lif_out)
    float* vst              = (float*)(w + (12 << 20));             // 32 KB
    unsigned int* cnt       = (unsigned int*)(w + (12 << 20) + (64 << 10));
    float* Iout             = (float*)(w + (13 << 20));

    const size_t base = (size_t)13 << 20;
    const size_t avail = (ws_size > base) ? (ws_size - base) : 0;
    int P = 1;
    if      (avail >= (size_t)B * 128 * T * NOUT * 4) P = 128;
    else if (avail >= (size_t)B *  16 * T * NOUT * 4) P = 16;
    else if (avail >= (size_t)B *   4 * T * NOUT * 4) P = 4;

    k_init<<<1, 64, 0, stream>>>(cnt);

    dim3 g1(NIN / 64, (B * S) / 64);
    k_gemm<<<g1, 256, 0, stream>>>(E, Win, bin, snn, B * S, NIN, D, 1);

    k_lif_inA<<<32, 256, 0, stream>>>(snn, sbits, cnt);
    k_lif_inB<<<B * S, 256, 0, stream>>>(sbits, msk);

    // snn is dead now: build transposed hi/lo bf16 split of W_conn in its place
    dim3 gp(NIN / 64, NOUT / 64);
    k_prep<<<gp, 256, 0, stream>>>(Wc, WhT, WlT);

    for (int c = 0; c < S / P; ++c) {
        dim3 gc((B * P * T) / 256, NOUT / 128);
        k_conn_mfma<<<gc, 256, 0, stream>>>(msk, WhT, WlT, Iout, c * P, P);
        k_lif_out<<<32, 256, 0, stream>>>(Iout, vst, sacc, cnt, c * P, P, c == 0 ? 1 : 0);
    }

    dim3 g2(D / 64, (B * S) / 64);
    k_gemm<<<g2, 256, 0, stream>>>(sacc, Wout, bout, out, B * S, D, NOUT, 0);

    k_rate<<<1, 64, 0, stream>>>(cnt, out + (size_t)B * S * D);
}